// Round 6
// baseline (269.926 us; speedup 1.0000x reference)
//
#include <hip/hip_runtime.h>

#define C_  8
#define NQ_ 16
#define NK_ 32
#define B_  128
#define D_  128
#define E_  512
#define H_  8
#define A_  64
#define O_  64

typedef __attribute__((ext_vector_type(4))) float f32x4;
typedef __attribute__((ext_vector_type(8))) short bf16x8;
typedef __attribute__((ext_vector_type(4))) short bf16x4;

__device__ __forceinline__ short f2bf(float f) {
    union { float f; unsigned u; } v; v.f = f;
    unsigned r = v.u + 0x7fffu + ((v.u >> 16) & 1u);
    return (short)(r >> 16);
}

// ---------------------------------------------------------------------------
// Kernel 1: fused PE + QKV projections — BARRIER-FREE, LDS-FREE.
// r5 falsified latency-hiding-by-occupancy (2.4x waves, same 91 us, HBM
// pinned at 2.75 TB/s): the limiter is barrier phase-convoying. This version
// deletes the convoy: each wave loads its MFMA fragments directly from
// global (A: contiguous dwordx4 pairs; B: 8 strided dwords — same 256 B/
// instr as the old staging loads), converts in-register, accumulates.
// Reuse the LDS used to provide (2x A, 2x B within block; 4x X across
// e-blocks) is served by L2 (64 KB W chunk, same XCD) and L3 (X = 41 MB).
// No __syncthreads anywhere -> waves phase-stagger, HBM queue never drains.
// ---------------------------------------------------------------------------
__global__ __launch_bounds__(256) void qkv_proj_kernel(
    const float* __restrict__ qin, const float* __restrict__ kin,
    const float* __restrict__ Wq, const float* __restrict__ Wk,
    const float* __restrict__ Wv,
    short* __restrict__ wsq, short* __restrict__ wsk, short* __restrict__ wsv)
{
    const int tid   = threadIdx.x;
    const int blk   = blockIdx.x;
    const int e_blk = blk & 3;
    const int unit  = blk >> 2;

    const float* X; const float* W; short* Y; int n; size_t ypitch;
    if (unit < C_ * NQ_) {
        const int c = unit >> 4;
        n = unit & 15;
        X = qin + (size_t)unit * B_ * D_;
        W = Wq  + (size_t)unit * D_ * E_;
        Y = wsq + (size_t)c * B_ * NQ_ * E_ + (size_t)n * E_;
        ypitch = (size_t)NQ_ * E_;
    } else if (unit < C_ * (NQ_ + NK_)) {
        const int u = unit - C_ * NQ_;
        const int c = u >> 5;
        n = u & 31;
        X = kin + (size_t)u * B_ * D_;
        W = Wk  + (size_t)u * D_ * E_;
        Y = wsk + (size_t)c * B_ * NK_ * E_ + (size_t)n * E_;
        ypitch = (size_t)NK_ * E_;
    } else {
        const int u = unit - C_ * (NQ_ + NK_);
        const int c = u >> 5;
        n = u & 31;
        X = kin + (size_t)u * B_ * D_;
        W = Wv  + (size_t)u * D_ * E_;
        Y = wsv + (size_t)c * B_ * NK_ * E_ + (size_t)n * E_;
        ypitch = (size_t)NK_ * E_;
    }

    const int wv   = tid >> 6;
    const int lane = tid & 63;
    const int lr   = lane & 15;
    const int quad = lane >> 4;
    const int wrow = (wv >> 1) * 64;
    const int wcol = (wv & 1) * 64;
    const int ecol = e_blk * 128 + wcol;

    f32x4 acc[4][4];
    #pragma unroll
    for (int m = 0; m < 4; ++m)
        #pragma unroll
        for (int nf = 0; nf < 4; ++nf)
            acc[m][nf] = (f32x4){0.f, 0.f, 0.f, 0.f};

    #pragma unroll
    for (int k0 = 0; k0 < D_; k0 += 64) {
        // PE for this 64-col k-half: lane holds pe[k0+lane] (identical math
        // to the original pe_buf fill; distribution via shfl).
        float peval;
        {
            const int d = k0 + lane;
            const float freq = expf((float)(d & ~1) * (-9.210340371976184f / (float)D_));
            const float arg  = (float)n * freq;
            peval = (d & 1) ? cosf(arg) : sinf(arg);
        }

        #pragma unroll
        for (int ks = 0; ks < 2; ++ks) {
            const int kc = k0 + ks * 32 + quad * 8;   // this lane's 8 k-cols

            // ---- A fragments: 2 contiguous dwordx4 per m -----------------
            f32x4 a0[4], a1[4];
            #pragma unroll
            for (int m = 0; m < 4; ++m) {
                const float* ar = X + (size_t)(wrow + m * 16 + lr) * D_ + kc;
                a0[m] = *(const f32x4*)ar;
                a1[m] = *(const f32x4*)(ar + 4);
            }

            // ---- B fragments: 8 strided dwords per nf --------------------
            float bw[4][8];
            #pragma unroll
            for (int nf = 0; nf < 4; ++nf) {
                const float* br = W + (size_t)kc * E_ + ecol + nf * 16 + lr;
                #pragma unroll
                for (int j = 0; j < 8; ++j)
                    bw[nf][j] = br[(size_t)j * E_];
            }

            // ---- PE values for cols kc..kc+7 (shared across m) -----------
            float pj[8];
            #pragma unroll
            for (int j = 0; j < 8; ++j)
                pj[j] = __shfl(peval, ks * 32 + quad * 8 + j);

            // ---- convert + MFMA -----------------------------------------
            bf16x8 af[4], bfr[4];
            #pragma unroll
            for (int m = 0; m < 4; ++m) {
                #pragma unroll
                for (int j = 0; j < 4; ++j) {
                    af[m][j]     = f2bf(a0[m][j] + pj[j]);
                    af[m][4 + j] = f2bf(a1[m][j] + pj[4 + j]);
                }
            }
            #pragma unroll
            for (int nf = 0; nf < 4; ++nf)
                #pragma unroll
                for (int j = 0; j < 8; ++j)
                    bfr[nf][j] = f2bf(bw[nf][j]);

            #pragma unroll
            for (int m = 0; m < 4; ++m)
                #pragma unroll
                for (int nf = 0; nf < 4; ++nf)
                    acc[m][nf] = __builtin_amdgcn_mfma_f32_16x16x32_bf16(
                        af[m], bfr[nf], acc[m][nf], 0, 0, 0);
        }
    }

    #pragma unroll
    for (int m = 0; m < 4; ++m)
        #pragma unroll
        for (int nf = 0; nf < 4; ++nf)
            #pragma unroll
            for (int r = 0; r < 4; ++r) {
                const int row = wrow + m * 16 + quad * 4 + r;
                const int col = e_blk * 128 + wcol + nf * 16 + lr;
                Y[(size_t)row * ypitch + col] = f2bf(acc[m][nf][r]);
            }
}

// ---------------------------------------------------------------------------
// Kernel 2: attention, 2-unit pipelined (round-4/5 verbatim).
// ---------------------------------------------------------------------------
__global__ __launch_bounds__(256) void attn_kernel(
    const short* __restrict__ wsq, const short* __restrict__ wsk,
    const short* __restrict__ wsv, short* __restrict__ wso)
{
    __shared__ __align__(16) short Ks[32][264];
    __shared__ __align__(16) short Vs[32][258];
    __shared__ __align__(16) short Ps[4][16][40];

    const int tid = threadIdx.x;
    const int pb  = blockIdx.x;              // 0..1023 = c*B + b
    const int b   = pb & (B_ - 1);
    const int c   = pb >> 7;

    const short* qb0 = wsq + ((size_t)(c * B_ + b) * NQ_) * E_;
    const short* kb0 = wsk + ((size_t)(c * B_ + b) * NK_) * E_;
    const short* vb0 = wsv + ((size_t)(c * B_ + b) * NK_) * E_;
    short*       ob0 = wso + ((size_t)(c * NQ_) * B_ + b) * E_;

    const int wv   = tid >> 6;
    const int lane = tid & 63;
    const int lr   = lane & 15;
    const int quad = lane >> 4;
    const int lcol = wv * 64;
    const int nloc = tid >> 5;               // 0..7
    const int ch   = tid & 31;               // 16B chunk in 512B slice

    auto loadKV = [&](const short* kb, const short* vb,
                      bf16x8 (&kr)[4], bf16x8 (&vr)[4]) {
        #pragma unroll
        for (int i = 0; i < 4; ++i)
            kr[i] = *(const bf16x8*)(kb + (size_t)(nloc + i * 8) * E_ + ch * 8);
        #pragma unroll
        for (int i = 0; i < 4; ++i)
            vr[i] = *(const bf16x8*)(vb + (size_t)(nloc + i * 8) * E_ + ch * 8);
    };
    auto writeKV = [&](bf16x8 (&kr)[4], bf16x8 (&vr)[4]) {
        #pragma unroll
        for (int i = 0; i < 4; ++i)
            *(bf16x8*)&Ks[nloc + i * 8][ch * 8] = kr[i];
        #pragma unroll
        for (int i = 0; i < 4; ++i)
            #pragma unroll
            for (int p = 0; p < 4; ++p)
                *(int*)&Vs[nloc + i * 8][ch * 8 + p * 2] = ((const int*)&vr[i])[p];
    };

    auto computeUnit = [&](const short* qb, short* ob) {
        const bf16x8 aq0 = *(const bf16x8*)(qb + (size_t)lr * E_ + lcol + quad * 8);
        const bf16x8 aq1 = *(const bf16x8*)(qb + (size_t)lr * E_ + lcol + 32 + quad * 8);

        f32x4 sacc0 = (f32x4){0.f, 0.f, 0.f, 0.f};
        f32x4 sacc1 = (f32x4){0.f, 0.f, 0.f, 0.f};
        {
            const int kc0 = lcol + quad * 8;
            sacc0 = __builtin_amdgcn_mfma_f32_16x16x32_bf16(aq0, *(const bf16x8*)&Ks[lr][kc0], sacc0, 0, 0, 0);
            sacc1 = __builtin_amdgcn_mfma_f32_16x16x32_bf16(aq0, *(const bf16x8*)&Ks[16 + lr][kc0], sacc1, 0, 0, 0);
            const int kc1 = lcol + 32 + quad * 8;
            sacc0 = __builtin_amdgcn_mfma_f32_16x16x32_bf16(aq1, *(const bf16x8*)&Ks[lr][kc1], sacc0, 0, 0, 0);
            sacc1 = __builtin_amdgcn_mfma_f32_16x16x32_bf16(aq1, *(const bf16x8*)&Ks[16 + lr][kc1], sacc1, 0, 0, 0);
        }

        float p0[4], p1[4];
        #pragma unroll
        for (int r = 0; r < 4; ++r) {
            const float v0 = sacc0[r] * 0.125f;
            const float v1 = sacc1[r] * 0.125f;
            float m = fmaxf(v0, v1);
            m = fmaxf(m, __shfl_xor(m, 1));
            m = fmaxf(m, __shfl_xor(m, 2));
            m = fmaxf(m, __shfl_xor(m, 4));
            m = fmaxf(m, __shfl_xor(m, 8));
            const float e0 = __expf(v0 - m);
            const float e1 = __expf(v1 - m);
            float s = e0 + e1;
            s += __shfl_xor(s, 1);
            s += __shfl_xor(s, 2);
            s += __shfl_xor(s, 4);
            s += __shfl_xor(s, 8);
            const float inv = 1.0f / s;
            p0[r] = e0 * inv;
            p1[r] = e1 * inv;
        }

        #pragma unroll
        for (int r = 0; r < 4; ++r) {
            Ps[wv][quad * 4 + r][lr]      = f2bf(p0[r]);
            Ps[wv][quad * 4 + r][16 + lr] = f2bf(p1[r]);
        }
        __syncthreads();
        const bf16x8 ap = *(const bf16x8*)&Ps[wv][lr][quad * 8];

        short* Osb = ((short*)Ks) + wv * 1024;   // Ks dead past Ps barrier

        #pragma unroll
        for (int t = 0; t < 4; ++t) {
            bf16x8 bvv;
            #pragma unroll
            for (int j = 0; j < 8; ++j)
                bvv[j] = Vs[quad * 8 + j][lcol + t * 16 + lr];
            f32x4 oacc = (f32x4){0.f, 0.f, 0.f, 0.f};
            oacc = __builtin_amdgcn_mfma_f32_16x16x32_bf16(ap, bvv, oacc, 0, 0, 0);
            #pragma unroll
            for (int r = 0; r < 4; ++r)
                Osb[(quad * 4 + r) * 64 + t * 16 + lr] = f2bf(oacc[r]);
        }

        const int q   = lane >> 2;
        const int seg = lane & 3;
        const bf16x8 oA = *(const bf16x8*)&Osb[q * 64 + seg * 16];
        const bf16x8 oB = *(const bf16x8*)&Osb[q * 64 + seg * 16 + 8];
        short* dst = ob + (size_t)q * (B_ * E_) + lcol + seg * 16;
        *(bf16x8*)dst       = oA;
        *(bf16x8*)(dst + 8) = oB;
    };

    bf16x8 kr0[4], vr0[4], kr1[4], vr1[4];
    loadKV(kb0, vb0, kr0, vr0);
    writeKV(kr0, vr0);
    __syncthreads();

    loadKV(kb0 + 256, vb0 + 256, kr1, vr1);
    computeUnit(qb0, ob0);
    __syncthreads();

    writeKV(kr1, vr1);
    __syncthreads();
    computeUnit(qb0 + 256, ob0 + 256);
}

// ---------------------------------------------------------------------------
// Kernel 3: output projection, single-stage full-K (round-4/5 verbatim).
// ---------------------------------------------------------------------------
__global__ __launch_bounds__(256) void out_proj_kernel(
    const short* __restrict__ wso, const float* __restrict__ Wp,
    float* __restrict__ out)
{
    __shared__ __align__(16) short Xlds[32 * 512];
    __shared__ __align__(16) short Wlds[32 * 512];

    const int tid = threadIdx.x;
    const int blk = blockIdx.x;
    const int cq  = blk >> 3;
    const int bh  = (blk >> 1) & 3;
    const int oh  = blk & 1;

    const short* Xb = wso + (size_t)cq * B_ * E_ + (size_t)bh * 32 * E_;
    const float* Wb = Wp  + (size_t)cq * E_ * O_ + oh * 32;
    float*       Ob = out + (size_t)cq * B_ * O_ + (size_t)bh * 32 * O_ + oh * 32;

    const int xrow = tid >> 3;
    const int xch  = tid & 7;
    const int o    = tid & 31;
    const int kg   = tid >> 5;

    bf16x8 xv[8];
    #pragma unroll
    for (int s = 0; s < 8; ++s)
        xv[s] = *(const bf16x8*)(Xb + (size_t)xrow * E_ + s * 64 + xch * 8);

    float wr[8][8];
    #pragma unroll
    for (int s = 0; s < 8; ++s)
        #pragma unroll
        for (int j = 0; j < 8; ++j)
            wr[s][j] = Wb[(size_t)(s * 64 + kg * 8 + j) * O_ + o];

    #pragma unroll
    for (int s = 0; s < 8; ++s) {
        const int g = (s * 8 + xch) ^ (xrow & 7);
        *(bf16x8*)&Xlds[xrow * 512 + g * 8] = xv[s];
    }
    #pragma unroll
    for (int s = 0; s < 8; ++s) {
        bf16x8 w8;
        #pragma unroll
        for (int j = 0; j < 8; ++j) w8[j] = f2bf(wr[s][j]);
        const int g = (s * 8 + kg) ^ (o & 7);
        *(bf16x8*)&Wlds[o * 512 + g * 8] = w8;
    }
    __syncthreads();

    const int wv   = tid >> 6;
    const int lane = tid & 63;
    const int lr   = lane & 15;
    const int quad = lane >> 4;
    const int rowh = wv >> 1;
    const int ohh  = wv & 1;
    const int arow = rowh * 16 + lr;
    const int brow = ohh * 16 + lr;

    f32x4 acc = (f32x4){0.f, 0.f, 0.f, 0.f};
    #pragma unroll
    for (int st = 0; st < 16; ++st) {
        const int ga = (st * 4 + quad) ^ (arow & 7);
        const int gb = (st * 4 + quad) ^ (brow & 7);
        const bf16x8 af  = *(const bf16x8*)&Xlds[arow * 512 + ga * 8];
        const bf16x8 bfr = *(const bf16x8*)&Wlds[brow * 512 + gb * 8];
        acc = __builtin_amdgcn_mfma_f32_16x16x32_bf16(af, bfr, acc, 0, 0, 0);
    }

    #pragma unroll
    for (int r = 0; r < 4; ++r)
        Ob[(size_t)(rowh * 16 + quad * 4 + r) * O_ + ohh * 16 + lr] = acc[r];
}

extern "C" void kernel_launch(void* const* d_in, const int* in_sizes, int n_in,
                              void* d_out, int out_size, void* d_ws, size_t ws_size,
                              hipStream_t stream) {
    const float* q  = (const float*)d_in[0];
    const float* k  = (const float*)d_in[1];
    const float* Wq = (const float*)d_in[2];
    const float* Wk = (const float*)d_in[3];
    const float* Wv = (const float*)d_in[4];
    const float* Wp = (const float*)d_in[5];
    float* out = (float*)d_out;

    const size_t sz_q = (size_t)C_ * NQ_ * B_ * E_;
    const size_t sz_k = (size_t)C_ * NK_ * B_ * E_;
    short* wsq = (short*)d_ws;
    short* wsk = wsq + sz_q;
    short* wsv = wsk + sz_k;
    short* wso = wsv + sz_k;

    qkv_proj_kernel<<<dim3(2560), dim3(256), 0, stream>>>(q, k, Wq, Wk, Wv, wsq, wsk, wsv);
    attn_kernel<<<dim3(1024), dim3(256), 0, stream>>>(wsq, wsk, wsv, wso);
    out_proj_kernel<<<dim3(1024), dim3(256), 0, stream>>>(wso, Wp, out);
}

// Round 7
// 257.666 us; speedup vs baseline: 1.0476x; 1.0476x over previous
//
#include <hip/hip_runtime.h>

#define C_  8
#define NQ_ 16
#define NK_ 32
#define B_  128
#define D_  128
#define E_  512
#define H_  8
#define A_  64
#define O_  64

typedef __attribute__((ext_vector_type(4))) float f32x4;
typedef __attribute__((ext_vector_type(8))) short bf16x8;
typedef __attribute__((ext_vector_type(4))) short bf16x4;

__device__ __forceinline__ short f2bf(float f) {
    union { float f; unsigned u; } v; v.f = f;
    unsigned r = v.u + 0x7fffu + ((v.u >> 16) & 1u);
    return (short)(r >> 16);
}

// async 16B global->LDS: no VGPR destination, counted by vmcnt. LDS dest is
// wave-uniform base + lane*16 (HW); global src is per-lane.
__device__ __forceinline__ void gl_lds16(const float* g, float* l) {
    __builtin_amdgcn_global_load_lds(
        (const __attribute__((address_space(1))) void*)g,
        (__attribute__((address_space(3))) void*)l, 16, 0, 0);
}

// ---------------------------------------------------------------------------
// Kernel 1: fused PE + QKV projections — async-staged 2-phase pipeline.
// r0-r6 isolated the limiter as MLP duty-cycle: VGPR-destined staging loads
// drain to zero during every convert/MFMA phase (HBM stuck at ~2.8 TB/s).
// Fix: global_load_lds staging (no VGPR dest) issued for step s+1 BEFORE
// computing step s — loads stay in flight under compute (guide T3 2-phase).
// K=128 split into 4 steps of 32; A(128x32 f32)+B(32x128 f32) double-buffered
// = 64 KB LDS, 2 blocks/CU. PE-add + bf16 cvt moved to the LDS->reg path
// (same f32 ops and order as r0 => bit-identical output). Staging sources
// pre-swizzled so linear LDS dest gives conflict-balanced reads.
// ---------------------------------------------------------------------------
__global__ __launch_bounds__(256) void qkv_proj_kernel(
    const float* __restrict__ qin, const float* __restrict__ kin,
    const float* __restrict__ Wq, const float* __restrict__ Wk,
    const float* __restrict__ Wv,
    short* __restrict__ wsq, short* __restrict__ wsk, short* __restrict__ wsv)
{
    __shared__ __align__(16) float Abuf[2][4096];  // [row][k32] chunk-swizzled
    __shared__ __align__(16) float Bbuf[2][4096];  // [k32][e128] granule-swizzled

    const int tid   = threadIdx.x;
    const int blk   = blockIdx.x;
    const int e_blk = blk & 3;
    const int unit  = blk >> 2;

    const float* X; const float* W; short* Y; int n; size_t ypitch;
    if (unit < C_ * NQ_) {
        const int c = unit >> 4;
        n = unit & 15;
        X = qin + (size_t)unit * B_ * D_;
        W = Wq  + (size_t)unit * D_ * E_;
        Y = wsq + (size_t)c * B_ * NQ_ * E_ + (size_t)n * E_;
        ypitch = (size_t)NQ_ * E_;
    } else if (unit < C_ * (NQ_ + NK_)) {
        const int u = unit - C_ * NQ_;
        const int c = u >> 5;
        n = u & 31;
        X = kin + (size_t)u * B_ * D_;
        W = Wk  + (size_t)u * D_ * E_;
        Y = wsk + (size_t)c * B_ * NK_ * E_ + (size_t)n * E_;
        ypitch = (size_t)NK_ * E_;
    } else {
        const int u = unit - C_ * (NQ_ + NK_);
        const int c = u >> 5;
        n = u & 31;
        X = kin + (size_t)u * B_ * D_;
        W = Wv  + (size_t)u * D_ * E_;
        Y = wsv + (size_t)c * B_ * NK_ * E_ + (size_t)n * E_;
        ypitch = (size_t)NK_ * E_;
    }

    const int wv   = tid >> 6;
    const int lane = tid & 63;
    const int lr   = lane & 15;
    const int quad = lane >> 4;
    const int wrow = (wv >> 1) * 64;
    const int wcol = (wv & 1) * 64;

    // staging lane decomposition
    const int l8   = lane >> 3;          // 0..7
    const int l7   = lane & 7;
    const int chnk = l7 >> 1;            // 0..3 (32B chunk within A row)
    const int hoff = (l7 & 1) * 4;       // half-chunk float offset
    const int l32  = lane >> 5;          // 0..1
    const int g31  = lane & 31;          // B granule index

    // PE values: lane holds pe[lane] and pe[64+lane] (same math as r0 pe_buf)
    float peA, peB;
    {
        const float base = -9.210340371976184f / (float)D_;
        float freq = expf((float)(lane & ~1) * base);
        float arg  = (float)n * freq;
        peA = (lane & 1) ? cosf(arg) : sinf(arg);
        const int d2 = 64 + lane;
        freq = expf((float)(d2 & ~1) * base);
        arg  = (float)n * freq;
        peB = (d2 & 1) ? cosf(arg) : sinf(arg);
    }

    // stage step s (k cols [s*32, s*32+32)) into buffer bf
    auto stage = [&](int bf, int s) {
        const int k0s = s * 32;
        #pragma unroll
        for (int i = 0; i < 4; ++i) {      // A: 128 rows x 32 k f32 = 16 KB
            const int row = i * 32 + wv * 8 + l8;
            const int cg  = chnk ^ (row & 3);              // chunk swizzle
            gl_lds16(X + (size_t)row * D_ + k0s + cg * 8 + hoff,
                     &Abuf[bf][i * 1024 + wv * 256]);
        }
        #pragma unroll
        for (int i = 0; i < 4; ++i) {      // B: 32 k x 128 e f32 = 16 KB
            const int k  = i * 8 + wv * 2 + l32;
            const int gg = g31 ^ (((k >> 3) & 3) << 1);    // granule swizzle
            gl_lds16(W + (size_t)(k0s + k) * E_ + e_blk * 128 + gg * 4,
                     &Bbuf[bf][i * 1024 + wv * 256]);
        }
    };

    f32x4 acc[4][4];
    #pragma unroll
    for (int m = 0; m < 4; ++m)
        #pragma unroll
        for (int nf = 0; nf < 4; ++nf)
            acc[m][nf] = (f32x4){0.f, 0.f, 0.f, 0.f};

    stage(0, 0);
    __syncthreads();   // drain prologue stage

    #pragma unroll
    for (int s = 0; s < 4; ++s) {
        const int cur = s & 1;
        if (s < 3) stage(cur ^ 1, s + 1);   // in flight under this step's compute

        // PE for this step's 8 k-cols per lane
        float pj[8];
        #pragma unroll
        for (int j = 0; j < 8; ++j) {
            const int kg = s * 32 + quad * 8 + j;
            pj[j] = (kg < 64) ? __shfl(peA, kg) : __shfl(peB, kg - 64);
        }

        // A fragments: b128 pair per m, +PE, ->bf16
        bf16x8 af[4];
        #pragma unroll
        for (int m = 0; m < 4; ++m) {
            const int row = wrow + m * 16 + lr;
            const int cg  = quad ^ (row & 3);
            const f32x4 x0 = *(const f32x4*)&Abuf[cur][row * 32 + cg * 8];
            const f32x4 x1 = *(const f32x4*)&Abuf[cur][row * 32 + cg * 8 + 4];
            #pragma unroll
            for (int j = 0; j < 4; ++j) {
                af[m][j]     = f2bf(x0[j] + pj[j]);
                af[m][4 + j] = f2bf(x1[j] + pj[4 + j]);
            }
        }

        // B fragments: 8 b32 per nf (banks spread by granule swizzle), ->bf16
        bf16x8 bfr[4];
        #pragma unroll
        for (int nf = 0; nf < 4; ++nf) {
            #pragma unroll
            for (int j = 0; j < 8; ++j) {
                const int kk = quad * 8 + j;
                const int el = (wcol + nf * 16 + lr) ^ (quad << 3);
                bfr[nf][j] = f2bf(Bbuf[cur][kk * 128 + el]);
            }
        }

        #pragma unroll
        for (int m = 0; m < 4; ++m)
            #pragma unroll
            for (int nf = 0; nf < 4; ++nf)
                acc[m][nf] = __builtin_amdgcn_mfma_f32_16x16x32_bf16(
                    af[m], bfr[nf], acc[m][nf], 0, 0, 0);

        __syncthreads();   // drains stage(s+1); guards buffer reuse
    }

    #pragma unroll
    for (int m = 0; m < 4; ++m)
        #pragma unroll
        for (int nf = 0; nf < 4; ++nf)
            #pragma unroll
            for (int r = 0; r < 4; ++r) {
                const int row = wrow + m * 16 + quad * 4 + r;
                const int col = e_blk * 128 + wcol + nf * 16 + lr;
                Y[(size_t)row * ypitch + col] = f2bf(acc[m][nf][r]);
            }
}

// ---------------------------------------------------------------------------
// Kernel 2: attention, 2-unit pipelined (round-4 verbatim).
// ---------------------------------------------------------------------------
__global__ __launch_bounds__(256) void attn_kernel(
    const short* __restrict__ wsq, const short* __restrict__ wsk,
    const short* __restrict__ wsv, short* __restrict__ wso)
{
    __shared__ __align__(16) short Ks[32][264];
    __shared__ __align__(16) short Vs[32][258];
    __shared__ __align__(16) short Ps[4][16][40];

    const int tid = threadIdx.x;
    const int pb  = blockIdx.x;              // 0..1023 = c*B + b
    const int b   = pb & (B_ - 1);
    const int c   = pb >> 7;

    const short* qb0 = wsq + ((size_t)(c * B_ + b) * NQ_) * E_;
    const short* kb0 = wsk + ((size_t)(c * B_ + b) * NK_) * E_;
    const short* vb0 = wsv + ((size_t)(c * B_ + b) * NK_) * E_;
    short*       ob0 = wso + ((size_t)(c * NQ_) * B_ + b) * E_;

    const int wv   = tid >> 6;
    const int lane = tid & 63;
    const int lr   = lane & 15;
    const int quad = lane >> 4;
    const int lcol = wv * 64;
    const int nloc = tid >> 5;               // 0..7
    const int ch   = tid & 31;               // 16B chunk in 512B slice

    auto loadKV = [&](const short* kb, const short* vb,
                      bf16x8 (&kr)[4], bf16x8 (&vr)[4]) {
        #pragma unroll
        for (int i = 0; i < 4; ++i)
            kr[i] = *(const bf16x8*)(kb + (size_t)(nloc + i * 8) * E_ + ch * 8);
        #pragma unroll
        for (int i = 0; i < 4; ++i)
            vr[i] = *(const bf16x8*)(vb + (size_t)(nloc + i * 8) * E_ + ch * 8);
    };
    auto writeKV = [&](bf16x8 (&kr)[4], bf16x8 (&vr)[4]) {
        #pragma unroll
        for (int i = 0; i < 4; ++i)
            *(bf16x8*)&Ks[nloc + i * 8][ch * 8] = kr[i];
        #pragma unroll
        for (int i = 0; i < 4; ++i)
            #pragma unroll
            for (int p = 0; p < 4; ++p)
                *(int*)&Vs[nloc + i * 8][ch * 8 + p * 2] = ((const int*)&vr[i])[p];
    };

    auto computeUnit = [&](const short* qb, short* ob) {
        const bf16x8 aq0 = *(const bf16x8*)(qb + (size_t)lr * E_ + lcol + quad * 8);
        const bf16x8 aq1 = *(const bf16x8*)(qb + (size_t)lr * E_ + lcol + 32 + quad * 8);

        f32x4 sacc0 = (f32x4){0.f, 0.f, 0.f, 0.f};
        f32x4 sacc1 = (f32x4){0.f, 0.f, 0.f, 0.f};
        {
            const int kc0 = lcol + quad * 8;
            sacc0 = __builtin_amdgcn_mfma_f32_16x16x32_bf16(aq0, *(const bf16x8*)&Ks[lr][kc0], sacc0, 0, 0, 0);
            sacc1 = __builtin_amdgcn_mfma_f32_16x16x32_bf16(aq0, *(const bf16x8*)&Ks[16 + lr][kc0], sacc1, 0, 0, 0);
            const int kc1 = lcol + 32 + quad * 8;
            sacc0 = __builtin_amdgcn_mfma_f32_16x16x32_bf16(aq1, *(const bf16x8*)&Ks[lr][kc1], sacc0, 0, 0, 0);
            sacc1 = __builtin_amdgcn_mfma_f32_16x16x32_bf16(aq1, *(const bf16x8*)&Ks[16 + lr][kc1], sacc1, 0, 0, 0);
        }

        float p0[4], p1[4];
        #pragma unroll
        for (int r = 0; r < 4; ++r) {
            const float v0 = sacc0[r] * 0.125f;
            const float v1 = sacc1[r] * 0.125f;
            float m = fmaxf(v0, v1);
            m = fmaxf(m, __shfl_xor(m, 1));
            m = fmaxf(m, __shfl_xor(m, 2));
            m = fmaxf(m, __shfl_xor(m, 4));
            m = fmaxf(m, __shfl_xor(m, 8));
            const float e0 = __expf(v0 - m);
            const float e1 = __expf(v1 - m);
            float s = e0 + e1;
            s += __shfl_xor(s, 1);
            s += __shfl_xor(s, 2);
            s += __shfl_xor(s, 4);
            s += __shfl_xor(s, 8);
            const float inv = 1.0f / s;
            p0[r] = e0 * inv;
            p1[r] = e1 * inv;
        }

        #pragma unroll
        for (int r = 0; r < 4; ++r) {
            Ps[wv][quad * 4 + r][lr]      = f2bf(p0[r]);
            Ps[wv][quad * 4 + r][16 + lr] = f2bf(p1[r]);
        }
        __syncthreads();
        const bf16x8 ap = *(const bf16x8*)&Ps[wv][lr][quad * 8];

        short* Osb = ((short*)Ks) + wv * 1024;   // Ks dead past Ps barrier

        #pragma unroll
        for (int t = 0; t < 4; ++t) {
            bf16x8 bvv;
            #pragma unroll
            for (int j = 0; j < 8; ++j)
                bvv[j] = Vs[quad * 8 + j][lcol + t * 16 + lr];
            f32x4 oacc = (f32x4){0.f, 0.f, 0.f, 0.f};
            oacc = __builtin_amdgcn_mfma_f32_16x16x32_bf16(ap, bvv, oacc, 0, 0, 0);
            #pragma unroll
            for (int r = 0; r < 4; ++r)
                Osb[(quad * 4 + r) * 64 + t * 16 + lr] = f2bf(oacc[r]);
        }

        const int q   = lane >> 2;
        const int seg = lane & 3;
        const bf16x8 oA = *(const bf16x8*)&Osb[q * 64 + seg * 16];
        const bf16x8 oB = *(const bf16x8*)&Osb[q * 64 + seg * 16 + 8];
        short* dst = ob + (size_t)q * (B_ * E_) + lcol + seg * 16;
        *(bf16x8*)dst       = oA;
        *(bf16x8*)(dst + 8) = oB;
    };

    bf16x8 kr0[4], vr0[4], kr1[4], vr1[4];
    loadKV(kb0, vb0, kr0, vr0);
    writeKV(kr0, vr0);
    __syncthreads();

    loadKV(kb0 + 256, vb0 + 256, kr1, vr1);
    computeUnit(qb0, ob0);
    __syncthreads();

    writeKV(kr1, vr1);
    __syncthreads();
    computeUnit(qb0 + 256, ob0 + 256);
}

// ---------------------------------------------------------------------------
// Kernel 3: output projection, single-stage full-K (round-4 verbatim).
// ---------------------------------------------------------------------------
__global__ __launch_bounds__(256) void out_proj_kernel(
    const short* __restrict__ wso, const float* __restrict__ Wp,
    float* __restrict__ out)
{
    __shared__ __align__(16) short Xlds[32 * 512];
    __shared__ __align__(16) short Wlds[32 * 512];

    const int tid = threadIdx.x;
    const int blk = blockIdx.x;
    const int cq  = blk >> 3;
    const int bh  = (blk >> 1) & 3;
    const int oh  = blk & 1;

    const short* Xb = wso + (size_t)cq * B_ * E_ + (size_t)bh * 32 * E_;
    const float* Wb = Wp  + (size_t)cq * E_ * O_ + oh * 32;
    float*       Ob = out + (size_t)cq * B_ * O_ + (size_t)bh * 32 * O_ + oh * 32;

    const int xrow = tid >> 3;
    const int xch  = tid & 7;
    const int o    = tid & 31;
    const int kg   = tid >> 5;

    bf16x8 xv[8];
    #pragma unroll
    for (int s = 0; s < 8; ++s)
        xv[s] = *(const bf16x8*)(Xb + (size_t)xrow * E_ + s * 64 + xch * 8);

    float wr[8][8];
    #pragma unroll
    for (int s = 0; s < 8; ++s)
        #pragma unroll
        for (int j = 0; j < 8; ++j)
            wr[s][j] = Wb[(size_t)(s * 64 + kg * 8 + j) * O_ + o];

    #pragma unroll
    for (int s = 0; s < 8; ++s) {
        const int g = (s * 8 + xch) ^ (xrow & 7);
        *(bf16x8*)&Xlds[xrow * 512 + g * 8] = xv[s];
    }
    #pragma unroll
    for (int s = 0; s < 8; ++s) {
        bf16x8 w8;
        #pragma unroll
        for (int j = 0; j < 8; ++j) w8[j] = f2bf(wr[s][j]);
        const int g = (s * 8 + kg) ^ (o & 7);
        *(bf16x8*)&Wlds[o * 512 + g * 8] = w8;
    }
    __syncthreads();

    const int wv   = tid >> 6;
    const int lane = tid & 63;
    const int lr   = lane & 15;
    const int quad = lane >> 4;
    const int rowh = wv >> 1;
    const int ohh  = wv & 1;
    const int arow = rowh * 16 + lr;
    const int brow = ohh * 16 + lr;

    f32x4 acc = (f32x4){0.f, 0.f, 0.f, 0.f};
    #pragma unroll
    for (int st = 0; st < 16; ++st) {
        const int ga = (st * 4 + quad) ^ (arow & 7);
        const int gb = (st * 4 + quad) ^ (brow & 7);
        const bf16x8 af  = *(const bf16x8*)&Xlds[arow * 512 + ga * 8];
        const bf16x8 bfr = *(const bf16x8*)&Wlds[brow * 512 + gb * 8];
        acc = __builtin_amdgcn_mfma_f32_16x16x32_bf16(af, bfr, acc, 0, 0, 0);
    }

    #pragma unroll
    for (int r = 0; r < 4; ++r)
        Ob[(size_t)(rowh * 16 + quad * 4 + r) * O_ + ohh * 16 + lr] = acc[r];
}

extern "C" void kernel_launch(void* const* d_in, const int* in_sizes, int n_in,
                              void* d_out, int out_size, void* d_ws, size_t ws_size,
                              hipStream_t stream) {
    const float* q  = (const float*)d_in[0];
    const float* k  = (const float*)d_in[1];
    const float* Wq = (const float*)d_in[2];
    const float* Wk = (const float*)d_in[3];
    const float* Wv = (const float*)d_in[4];
    const float* Wp = (const float*)d_in[5];
    float* out = (float*)d_out;

    const size_t sz_q = (size_t)C_ * NQ_ * B_ * E_;
    const size_t sz_k = (size_t)C_ * NK_ * B_ * E_;
    short* wsq = (short*)d_ws;
    short* wsk = wsq + sz_q;
    short* wsv = wsk + sz_k;
    short* wso = wsv + sz_k;

    qkv_proj_kernel<<<dim3(2560), dim3(256), 0, stream>>>(q, k, Wq, Wk, Wv, wsq, wsk, wsv);
    attn_kernel<<<dim3(1024), dim3(256), 0, stream>>>(wsq, wsk, wsv, wso);
    out_proj_kernel<<<dim3(1024), dim3(256), 0, stream>>>(wso, Wp, out);
}